// Round 1
// baseline (66609.052 us; speedup 1.0000x reference)
//
#include <hip/hip_runtime.h>

// GRUModel: 2-layer GRU (T=16384, IN=512, H=1024) + BatchNorm(train) + FC(H->1)
//
// Strategy: single persistent kernel, 128 blocks (64 layer0 + 64 layer1), each
// block owns 16 hidden channels. All weights live in VGPRs as f16 pairs
// (v_dot2_f32_f16). Layers run pipelined: tick t computes h1[t] (layer0) and
// h2[t-1] (layer1). Cross-block exchange of h via write-once f16 pairs in ws,
// system-scope u32 atomics (bypass non-coherent per-XCD L2); consumers poll
// their own input slices against the f16-NaN sentinel 0x7F7F (memset 0x7F).
// Real gate outputs (sigmoid/tanh products) are never NaN, so data==flag.
// BN stats accumulate in registers in layer1 blocks; FC kernel finishes.

#define TT 16384
#define IND 512
#define HD 1024

typedef _Float16 h2_t __attribute__((ext_vector_type(2)));

__device__ __forceinline__ float fdot2f(h2_t a, h2_t b, float c) {
#if __has_builtin(__builtin_amdgcn_fdot2)
  return __builtin_amdgcn_fdot2(a, b, c, false);
#else
  return c + (float)a.x * (float)b.x + (float)a.y * (float)b.y;
#endif
}

__device__ __forceinline__ h2_t cvt2(float a, float b) {
  h2_t r; r.x = (_Float16)a; r.y = (_Float16)b; return r;
}

__device__ __forceinline__ bool ok64(unsigned long long v) {
  return ((unsigned)v != 0x7F7F7F7Fu) && ((unsigned)(v >> 32) != 0x7F7F7F7Fu);
}

__device__ __forceinline__ float sigm(float v) { return 1.f / (1.f + __expf(-v)); }
__device__ __forceinline__ float tanh_f(float v) {
  v = fminf(fmaxf(v, -15.f), 15.f);
  float e = __expf(2.f * v);
  return (e - 1.f) / (e + 1.f);
}

__launch_bounds__(256, 1)
__global__ void gru_persistent(
    const float* __restrict__ x,
    const float* __restrict__ wih0, const float* __restrict__ whh0,
    const float* __restrict__ bih0, const float* __restrict__ bhh0,
    const float* __restrict__ wih1, const float* __restrict__ whh1,
    const float* __restrict__ bih1, const float* __restrict__ bhh1,
    unsigned* h1u, unsigned* h2u, float* sums)
{
  const int bid = blockIdx.x;
  const int tid = threadIdx.x;
  const int wave = tid >> 6;
  const int lane = tid & 63;
  __shared__ float4 gh[16];

  if (bid < 64) {
    // ---------------- layer 0 ----------------
    const int cblk = bid * 16;
    const int ch = cblk + wave * 4;   // this wave's 4 channels
    // weights in registers: x-part slice 8 f16 per gate, h-part slice 16 f16
    h2_t Wx[4][3][4];
    h2_t Wh[4][3][8];
#pragma unroll
    for (int cc = 0; cc < 4; ++cc) {
      const int c = ch + cc;
#pragma unroll
      for (int g = 0; g < 3; ++g) {
        const float* pr = wih0 + (size_t)(g * HD + c) * IND + 8 * lane;
#pragma unroll
        for (int j = 0; j < 4; ++j) Wx[cc][g][j] = cvt2(pr[2 * j], pr[2 * j + 1]);
        const float* ph = whh0 + (size_t)(g * HD + c) * HD + 16 * lane;
#pragma unroll
        for (int j = 0; j < 8; ++j) Wh[cc][g][j] = cvt2(ph[2 * j], ph[2 * j + 1]);
      }
    }
    float bR = 0.f, bZ = 0.f, bNx = 0.f, bNh = 0.f;
    if (lane < 4) {
      const int c = ch + lane;
      bR = bih0[c] + bhh0[c];
      bZ = bih0[HD + c] + bhh0[HD + c];
      bNx = bih0[2 * HD + c];
      bNh = bhh0[2 * HD + c];
    }
    float hprev = 0.f;
    for (int t = 0; t <= TT; ++t) {
      const bool active = (t < TT);
      if (active) {
        // x[t] preload (plain cached loads, issued before the poll)
        const float* px = x + (size_t)t * IND + 8 * lane;
        float4 xa = *(const float4*)px;
        float4 xb = *(const float4*)(px + 4);
        // poll h1 slot t ( = h1[t-1]; slot 0 pre-zeroed )
        const unsigned long long* p1 =
            (const unsigned long long*)h1u + (size_t)t * 256 + 4 * lane;
        unsigned long long hv[4];
        bool ok;
        do {
          ok = true;
#pragma unroll
          for (int i = 0; i < 4; ++i) {
            hv[i] = __hip_atomic_load(p1 + i, __ATOMIC_RELAXED, __HIP_MEMORY_SCOPE_SYSTEM);
            ok = ok & ok64(hv[i]);
          }
        } while (__any(!ok));
        h2_t xv[4];
        xv[0] = cvt2(xa.x, xa.y); xv[1] = cvt2(xa.z, xa.w);
        xv[2] = cvt2(xb.x, xb.y); xv[3] = cvt2(xb.z, xb.w);
        h2_t hh[8];
#pragma unroll
        for (int i = 0; i < 4; ++i) {
          hh[2 * i]     = __builtin_bit_cast(h2_t, (unsigned)hv[i]);
          hh[2 * i + 1] = __builtin_bit_cast(h2_t, (unsigned)(hv[i] >> 32));
        }
#pragma unroll
        for (int cc = 0; cc < 4; ++cc) {
          float aR = 0.f, aZ = 0.f, aNx = 0.f, aNh = 0.f;
#pragma unroll
          for (int j = 0; j < 4; ++j) {
            aR  = fdot2f(Wx[cc][0][j], xv[j], aR);
            aZ  = fdot2f(Wx[cc][1][j], xv[j], aZ);
            aNx = fdot2f(Wx[cc][2][j], xv[j], aNx);
          }
#pragma unroll
          for (int j = 0; j < 8; ++j) {
            aR  = fdot2f(Wh[cc][0][j], hh[j], aR);
            aZ  = fdot2f(Wh[cc][1][j], hh[j], aZ);
            aNh = fdot2f(Wh[cc][2][j], hh[j], aNh);
          }
#pragma unroll
          for (int m = 32; m >= 1; m >>= 1) {
            aR  += __shfl_xor(aR, m);
            aZ  += __shfl_xor(aZ, m);
            aNx += __shfl_xor(aNx, m);
            aNh += __shfl_xor(aNh, m);
          }
          if (lane == cc)
            gh[wave * 4 + cc] = make_float4(aR + bR, aZ + bZ, aNx + bNx, aNh + bNh);
        }
      }
      __syncthreads();
      if (active && tid < 16) {
        float4 s = gh[tid];
        float r = sigm(s.x);
        float z = sigm(s.y);
        float n = tanh_f(s.z + r * s.w);
        float hn = (1.f - z) * n + z * hprev;
        hprev = hn;
        unsigned hb = (unsigned)__builtin_bit_cast(unsigned short, (_Float16)hn);
        unsigned oth = __shfl_down(hb, 1);
        if (!(tid & 1)) {
          unsigned pk = hb | (oth << 16);
          __hip_atomic_store(h1u + (size_t)(t + 1) * 512 + (cblk >> 1) + (tid >> 1), pk,
                             __ATOMIC_RELAXED, __HIP_MEMORY_SCOPE_SYSTEM);
        }
      }
    }
  } else {
    // ---------------- layer 1 ----------------
    const int cblk = (bid - 64) * 16;
    const int ch = cblk + wave * 4;
    // parts: 0=r_ih 1=r_hh 2=z_ih 3=z_hh 4=n_ih 5=n_hh ; 16-f16 slice each
    h2_t W[4][6][8];
#pragma unroll
    for (int cc = 0; cc < 4; ++cc) {
      const int c = ch + cc;
#pragma unroll
      for (int g = 0; g < 3; ++g) {
        const float* pi = wih1 + (size_t)(g * HD + c) * HD + 16 * lane;
        const float* ph = whh1 + (size_t)(g * HD + c) * HD + 16 * lane;
#pragma unroll
        for (int j = 0; j < 8; ++j) {
          W[cc][2 * g][j]     = cvt2(pi[2 * j], pi[2 * j + 1]);
          W[cc][2 * g + 1][j] = cvt2(ph[2 * j], ph[2 * j + 1]);
        }
      }
    }
    float bR = 0.f, bZ = 0.f, bNx = 0.f, bNh = 0.f;
    if (lane < 4) {
      const int c = ch + lane;
      bR = bih1[c] + bhh1[c];
      bZ = bih1[HD + c] + bhh1[HD + c];
      bNx = bih1[2 * HD + c];
      bNh = bhh1[2 * HD + c];
    }
    float hprev = 0.f, ssum = 0.f, ssq = 0.f;
    for (int t = 0; t <= TT; ++t) {
      const bool active = (t >= 1);   // tick t computes h2[t-1]
      if (active) {
        const unsigned long long* p1 =
            (const unsigned long long*)h1u + (size_t)t * 256 + 4 * lane;       // h1[t-1]
        const unsigned long long* p2 =
            (const unsigned long long*)h2u + (size_t)(t - 1) * 256 + 4 * lane; // h2[t-2]
        unsigned long long va[4], vb[4];
        bool ok;
        do {
          ok = true;
#pragma unroll
          for (int i = 0; i < 4; ++i) {
            va[i] = __hip_atomic_load(p1 + i, __ATOMIC_RELAXED, __HIP_MEMORY_SCOPE_SYSTEM);
            ok = ok & ok64(va[i]);
          }
#pragma unroll
          for (int i = 0; i < 4; ++i) {
            vb[i] = __hip_atomic_load(p2 + i, __ATOMIC_RELAXED, __HIP_MEMORY_SCOPE_SYSTEM);
            ok = ok & ok64(vb[i]);
          }
        } while (__any(!ok));
        h2_t g1[8], g2[8];
#pragma unroll
        for (int i = 0; i < 4; ++i) {
          g1[2 * i]     = __builtin_bit_cast(h2_t, (unsigned)va[i]);
          g1[2 * i + 1] = __builtin_bit_cast(h2_t, (unsigned)(va[i] >> 32));
          g2[2 * i]     = __builtin_bit_cast(h2_t, (unsigned)vb[i]);
          g2[2 * i + 1] = __builtin_bit_cast(h2_t, (unsigned)(vb[i] >> 32));
        }
#pragma unroll
        for (int cc = 0; cc < 4; ++cc) {
          float aR = 0.f, aZ = 0.f, aNx = 0.f, aNh = 0.f;
#pragma unroll
          for (int j = 0; j < 8; ++j) {
            aR  = fdot2f(W[cc][0][j], g1[j], aR);
            aR  = fdot2f(W[cc][1][j], g2[j], aR);
            aZ  = fdot2f(W[cc][2][j], g1[j], aZ);
            aZ  = fdot2f(W[cc][3][j], g2[j], aZ);
            aNx = fdot2f(W[cc][4][j], g1[j], aNx);
            aNh = fdot2f(W[cc][5][j], g2[j], aNh);
          }
#pragma unroll
          for (int m = 32; m >= 1; m >>= 1) {
            aR  += __shfl_xor(aR, m);
            aZ  += __shfl_xor(aZ, m);
            aNx += __shfl_xor(aNx, m);
            aNh += __shfl_xor(aNh, m);
          }
          if (lane == cc)
            gh[wave * 4 + cc] = make_float4(aR + bR, aZ + bZ, aNx + bNx, aNh + bNh);
        }
      }
      __syncthreads();
      if (active && tid < 16) {
        float4 s = gh[tid];
        float r = sigm(s.x);
        float z = sigm(s.y);
        float n = tanh_f(s.z + r * s.w);
        float hn = (1.f - z) * n + z * hprev;
        hprev = hn;
        ssum += hn;
        ssq += hn * hn;
        unsigned hb = (unsigned)__builtin_bit_cast(unsigned short, (_Float16)hn);
        unsigned oth = __shfl_down(hb, 1);
        if (!(tid & 1)) {
          unsigned pk = hb | (oth << 16);
          __hip_atomic_store(h2u + (size_t)t * 512 + (cblk >> 1) + (tid >> 1), pk,
                             __ATOMIC_RELAXED, __HIP_MEMORY_SCOPE_SYSTEM);
        }
      }
    }
    if (tid < 16) {
      sums[cblk + tid] = ssum;
      sums[HD + cblk + tid] = ssq;
    }
  }
}

// y[t] = K + sum_c h2[t,c]*A[c];  A = rsqrt(var+eps)*gamma*fc_w,
// K = fc_b + sum_c (beta*fc_w - mu*A)
__launch_bounds__(256)
__global__ void fc_bn_kernel(const unsigned* __restrict__ h2u, const float* __restrict__ sums,
                             const float* __restrict__ gamma, const float* __restrict__ beta,
                             const float* __restrict__ fcw, const float* __restrict__ fcb,
                             float* __restrict__ out)
{
  const int tid = threadIdx.x;
  const int wave = tid >> 6;
  const int lane = tid & 63;
  float A[16];
  float kp = 0.f;
#pragma unroll
  for (int j = 0; j < 16; ++j) {
    const int c = 16 * lane + j;
    float mu = sums[c] * (1.f / TT);
    float var = fmaxf(sums[HD + c] * (1.f / TT) - mu * mu, 0.f);
    float rs = rsqrtf(var + 1e-5f);
    float a = rs * gamma[c] * fcw[c];
    A[j] = a;
    kp += beta[c] * fcw[c] - mu * a;
  }
#pragma unroll
  for (int m = 32; m >= 1; m >>= 1) kp += __shfl_xor(kp, m);
  const float K = kp + fcb[0];
  const int tbase = (blockIdx.x * 4 + wave) * 16;
  for (int mm = 0; mm < 16; ++mm) {
    const int t = tbase + mm;
    const unsigned* p = h2u + (size_t)(t + 1) * 512 + 8 * lane;
    float d = 0.f;
#pragma unroll
    for (int j = 0; j < 8; ++j) {
      h2_t hp = __builtin_bit_cast(h2_t, p[j]);
      d += (float)hp.x * A[2 * j] + (float)hp.y * A[2 * j + 1];
    }
#pragma unroll
    for (int m = 32; m >= 1; m >>= 1) d += __shfl_xor(d, m);
    if (lane == 0) out[t] = K + d;
  }
}

extern "C" void kernel_launch(void* const* d_in, const int* in_sizes, int n_in,
                              void* d_out, int out_size, void* d_ws, size_t ws_size,
                              hipStream_t stream) {
  const float* x    = (const float*)d_in[0];
  const float* wih0 = (const float*)d_in[1];
  const float* whh0 = (const float*)d_in[2];
  const float* bih0 = (const float*)d_in[3];
  const float* bhh0 = (const float*)d_in[4];
  const float* wih1 = (const float*)d_in[5];
  const float* whh1 = (const float*)d_in[6];
  const float* bih1 = (const float*)d_in[7];
  const float* bhh1 = (const float*)d_in[8];
  const float* gamma = (const float*)d_in[9];
  const float* beta  = (const float*)d_in[10];
  const float* fcw   = (const float*)d_in[11];
  const float* fcb   = (const float*)d_in[12];

  const size_t HIST = (size_t)(TT + 1) * HD * 2;   // 33,556,480 B per history
  unsigned* h1u = (unsigned*)d_ws;
  unsigned* h2u = (unsigned*)((char*)d_ws + HIST);
  float* sums = (float*)((char*)d_ws + 2 * HIST);

  // slot 0 = h[-1] = 0 ; slots 1..TT = f16 NaN sentinel (0x7F7F)
  hipMemsetAsync(h1u, 0, (size_t)HD * 2, stream);
  hipMemsetAsync((char*)h1u + HD * 2, 0x7F, (size_t)TT * HD * 2, stream);
  hipMemsetAsync(h2u, 0, (size_t)HD * 2, stream);
  hipMemsetAsync((char*)h2u + HD * 2, 0x7F, (size_t)TT * HD * 2, stream);

  gru_persistent<<<128, 256, 0, stream>>>(x, wih0, whh0, bih0, bhh0,
                                          wih1, whh1, bih1, bhh1,
                                          h1u, h2u, sums);
  fc_bn_kernel<<<256, 256, 0, stream>>>(h2u, sums, gamma, beta, fcw, fcb,
                                        (float*)d_out);
}

// Round 2
// 55753.033 us; speedup vs baseline: 1.1947x; 1.1947x over previous
//
#include <hip/hip_runtime.h>

// GRUModel: 2-layer GRU (T=16384, IN=512, H=1024) + BatchNorm(train) + FC(H->1)
//
// Persistent kernel, 128 blocks (64 layer0 + 64 layer1), 4 waves each; every
// wave owns 4 contiguous channels end-to-end (weights in VGPRs as f16 pairs,
// v_dot2_f32_f16). No __syncthreads, no LDS: wave-local butterfly reduction,
// gates computed redundantly in all lanes, one atomic u64 store per wave
// (4 channels packed f16). Cross-block exchange via AGENT-scope relaxed
// atomics on ws; consumers poll their own u64 granules against the f16-NaN
// sentinel 0x7F7F7F7F (memset 0x7F). Producers store whole u64s atomically,
// so checking the low u32 suffices. Gate outputs are never NaN => data==flag.

#define TT 16384
#define IND 512
#define HD 1024

typedef _Float16 h2_t __attribute__((ext_vector_type(2)));

static __device__ __forceinline__ float fdot2f(h2_t a, h2_t b, float c) {
  return __builtin_amdgcn_fdot2(a, b, c, false);
}
static __device__ __forceinline__ h2_t cvt2(float a, float b) {
  h2_t r; r.x = (_Float16)a; r.y = (_Float16)b; return r;
}
static __device__ __forceinline__ float sigm(float v) { return 1.f / (1.f + __expf(-v)); }
static __device__ __forceinline__ float tanh_f(float v) {
  v = fminf(fmaxf(v, -15.f), 15.f);
  float e = __expf(2.f * v);
  return (e - 1.f) / (e + 1.f);
}

// Reduce 4 per-lane partials across 64 lanes. Returns (R,Z,Nx,Nh) totals in
// all lanes. 11 DS ops instead of 24 (pair-merge butterfly).
static __device__ __forceinline__ float4 reduce4(float aR, float aZ, float aNx,
                                                 float aNh, int lane) {
  const bool s1 = lane & 1;
  float x1 = s1 ? aZ : aR, y1 = s1 ? aR : aZ;
  x1 += __shfl_xor(y1, 1);
  float x2 = s1 ? aNh : aNx, y2 = s1 ? aNx : aNh;
  x2 += __shfl_xor(y2, 1);
  const bool s2 = lane & 2;
  float z = s2 ? x2 : x1, w = s2 ? x1 : x2;
  z += __shfl_xor(w, 2);
  z += __shfl_xor(z, 4);
  z += __shfl_xor(z, 8);
  z += __shfl_xor(z, 16);
  z += __shfl_xor(z, 32);
  // lane%4==0 holds sumR, ==1 sumZ, ==2 sumNx, ==3 sumNh
  return make_float4(__shfl(z, 0), __shfl(z, 1), __shfl(z, 2), __shfl(z, 3));
}

static __device__ __forceinline__ unsigned long long pack4(float h0, float h1,
                                                           float h2, float h3) {
  unsigned lo = (unsigned)__builtin_bit_cast(unsigned short, (_Float16)h0) |
                ((unsigned)__builtin_bit_cast(unsigned short, (_Float16)h1) << 16);
  unsigned hi = (unsigned)__builtin_bit_cast(unsigned short, (_Float16)h2) |
                ((unsigned)__builtin_bit_cast(unsigned short, (_Float16)h3) << 16);
  return (unsigned long long)lo | ((unsigned long long)hi << 32);
}

__launch_bounds__(256, 1)
__global__ void gru_persistent(
    const float* __restrict__ x,
    const float* __restrict__ wih0, const float* __restrict__ whh0,
    const float* __restrict__ bih0, const float* __restrict__ bhh0,
    const float* __restrict__ wih1, const float* __restrict__ whh1,
    const float* __restrict__ bih1, const float* __restrict__ bhh1,
    unsigned long long* h1u, unsigned long long* h2u, float* sums)
{
  const int bid = blockIdx.x;
  const int tid = threadIdx.x;
  const int wave = tid >> 6;
  const int lane = tid & 63;

  if (bid < 64) {
    // ---------------- layer 0 : wave owns channels ch..ch+3 ----------------
    const int ch = bid * 16 + wave * 4;
    h2_t Wx[4][3][4];   // x-part: 8 f16 per gate per channel
    h2_t Wh[4][3][8];   // h-part: 16 f16 per gate per channel
    float bRv[4], bZv[4], bNxv[4], bNhv[4];
#pragma unroll
    for (int cc = 0; cc < 4; ++cc) {
      const int c = ch + cc;
#pragma unroll
      for (int g = 0; g < 3; ++g) {
        const float* pr = wih0 + (size_t)(g * HD + c) * IND + 8 * lane;
#pragma unroll
        for (int j = 0; j < 4; ++j) Wx[cc][g][j] = cvt2(pr[2 * j], pr[2 * j + 1]);
        const float* ph = whh0 + (size_t)(g * HD + c) * HD + 16 * lane;
#pragma unroll
        for (int j = 0; j < 8; ++j) Wh[cc][g][j] = cvt2(ph[2 * j], ph[2 * j + 1]);
      }
      bRv[cc]  = bih0[c] + bhh0[c];
      bZv[cc]  = bih0[HD + c] + bhh0[HD + c];
      bNxv[cc] = bih0[2 * HD + c];
      bNhv[cc] = bhh0[2 * HD + c];
    }
    float hprev[4] = {0.f, 0.f, 0.f, 0.f};
    // software-pipelined x row
    const float* px0 = x + 8 * lane;
    float4 xa = *(const float4*)px0;
    float4 xb = *(const float4*)(px0 + 4);
    for (int t = 0; t < TT; ++t) {
      h2_t xv[4];
      xv[0] = cvt2(xa.x, xa.y); xv[1] = cvt2(xa.z, xa.w);
      xv[2] = cvt2(xb.x, xb.y); xv[3] = cvt2(xb.z, xb.w);
      if (t + 1 < TT) {
        const float* pn = x + (size_t)(t + 1) * IND + 8 * lane;
        xa = *(const float4*)pn;
        xb = *(const float4*)(pn + 4);
      }
      // x-part partials (off critical path)
      float aR[4], aZ[4], aNx[4], aNh[4];
#pragma unroll
      for (int cc = 0; cc < 4; ++cc) {
        float r = 0.f, z = 0.f, n = 0.f;
#pragma unroll
        for (int j = 0; j < 4; ++j) {
          r = fdot2f(Wx[cc][0][j], xv[j], r);
          z = fdot2f(Wx[cc][1][j], xv[j], z);
          n = fdot2f(Wx[cc][2][j], xv[j], n);
        }
        aR[cc] = r; aZ[cc] = z; aNx[cc] = n; aNh[cc] = 0.f;
      }
      // poll h1[t-1] (slot t; slot 0 pre-zeroed)
      const unsigned long long* p1 = h1u + (size_t)t * 256 + 4 * lane;
      unsigned long long hv[4];
      bool ok;
      do {
        ok = true;
#pragma unroll
        for (int i = 0; i < 4; ++i) {
          hv[i] = __hip_atomic_load(p1 + i, __ATOMIC_RELAXED, __HIP_MEMORY_SCOPE_AGENT);
          ok = ok & ((unsigned)hv[i] != 0x7F7F7F7Fu);
        }
      } while (__any(!ok));
      h2_t hh[8];
#pragma unroll
      for (int i = 0; i < 4; ++i) {
        hh[2 * i]     = __builtin_bit_cast(h2_t, (unsigned)hv[i]);
        hh[2 * i + 1] = __builtin_bit_cast(h2_t, (unsigned)(hv[i] >> 32));
      }
#pragma unroll
      for (int cc = 0; cc < 4; ++cc) {
        float r = aR[cc], z = aZ[cc], n = aNh[cc];
#pragma unroll
        for (int j = 0; j < 8; ++j) {
          r = fdot2f(Wh[cc][0][j], hh[j], r);
          z = fdot2f(Wh[cc][1][j], hh[j], z);
          n = fdot2f(Wh[cc][2][j], hh[j], n);
        }
        aR[cc] = r; aZ[cc] = z; aNh[cc] = n;
      }
      float hn[4];
#pragma unroll
      for (int cc = 0; cc < 4; ++cc) {
        float4 s = reduce4(aR[cc], aZ[cc], aNx[cc], aNh[cc], lane);
        float r = sigm(s.x + bRv[cc]);
        float zz = sigm(s.y + bZv[cc]);
        float n = tanh_f(s.z + bNxv[cc] + r * (s.w + bNhv[cc]));
        hn[cc] = (1.f - zz) * n + zz * hprev[cc];
        hprev[cc] = hn[cc];
      }
      if (lane == 0) {
        unsigned long long pk = pack4(hn[0], hn[1], hn[2], hn[3]);
        __hip_atomic_store(h1u + (size_t)(t + 1) * 256 + (ch >> 2), pk,
                           __ATOMIC_RELAXED, __HIP_MEMORY_SCOPE_AGENT);
      }
    }
  } else {
    // ---------------- layer 1 : wave owns channels ch..ch+3 ----------------
    const int ch = (bid - 64) * 16 + wave * 4;
    // parts: 0=r_ih 1=r_hh 2=z_ih 3=z_hh 4=n_ih 5=n_hh ; 16-f16 slice each
    h2_t W[4][6][8];
    float bRv[4], bZv[4], bNxv[4], bNhv[4];
#pragma unroll
    for (int cc = 0; cc < 4; ++cc) {
      const int c = ch + cc;
#pragma unroll
      for (int g = 0; g < 3; ++g) {
        const float* pi = wih1 + (size_t)(g * HD + c) * HD + 16 * lane;
        const float* ph = whh1 + (size_t)(g * HD + c) * HD + 16 * lane;
#pragma unroll
        for (int j = 0; j < 8; ++j) {
          W[cc][2 * g][j]     = cvt2(pi[2 * j], pi[2 * j + 1]);
          W[cc][2 * g + 1][j] = cvt2(ph[2 * j], ph[2 * j + 1]);
        }
      }
      bRv[cc]  = bih1[c] + bhh1[c];
      bZv[cc]  = bih1[HD + c] + bhh1[HD + c];
      bNxv[cc] = bih1[2 * HD + c];
      bNhv[cc] = bhh1[2 * HD + c];
    }
    float hprev[4] = {0.f, 0.f, 0.f, 0.f};
    float ssum[4] = {0.f, 0.f, 0.f, 0.f};
    float ssq[4] = {0.f, 0.f, 0.f, 0.f};
    for (int t = 1; t <= TT; ++t) {
      // poll h1[t-1] (slot t) FIRST — layer0 free-runs ahead, usually ready
      const unsigned long long* p1 = h1u + (size_t)t * 256 + 4 * lane;
      unsigned long long va[4];
      bool ok;
      do {
        ok = true;
#pragma unroll
        for (int i = 0; i < 4; ++i) {
          va[i] = __hip_atomic_load(p1 + i, __ATOMIC_RELAXED, __HIP_MEMORY_SCOPE_AGENT);
          ok = ok & ((unsigned)va[i] != 0x7F7F7F7Fu);
        }
      } while (__any(!ok));
      h2_t g1[8];
#pragma unroll
      for (int i = 0; i < 4; ++i) {
        g1[2 * i]     = __builtin_bit_cast(h2_t, (unsigned)va[i]);
        g1[2 * i + 1] = __builtin_bit_cast(h2_t, (unsigned)(va[i] >> 32));
      }
      float aR[4], aZ[4], aNx[4], aNh[4];
#pragma unroll
      for (int cc = 0; cc < 4; ++cc) {
        float r = 0.f, z = 0.f, n = 0.f;
#pragma unroll
        for (int j = 0; j < 8; ++j) {
          r = fdot2f(W[cc][0][j], g1[j], r);
          z = fdot2f(W[cc][2][j], g1[j], z);
          n = fdot2f(W[cc][4][j], g1[j], n);
        }
        aR[cc] = r; aZ[cc] = z; aNx[cc] = n; aNh[cc] = 0.f;
      }
      // poll h2[t-2] (slot t-1) — the binding recurrence
      const unsigned long long* p2 = h2u + (size_t)(t - 1) * 256 + 4 * lane;
      unsigned long long vb[4];
      do {
        ok = true;
#pragma unroll
        for (int i = 0; i < 4; ++i) {
          vb[i] = __hip_atomic_load(p2 + i, __ATOMIC_RELAXED, __HIP_MEMORY_SCOPE_AGENT);
          ok = ok & ((unsigned)vb[i] != 0x7F7F7F7Fu);
        }
      } while (__any(!ok));
      h2_t g2[8];
#pragma unroll
      for (int i = 0; i < 4; ++i) {
        g2[2 * i]     = __builtin_bit_cast(h2_t, (unsigned)vb[i]);
        g2[2 * i + 1] = __builtin_bit_cast(h2_t, (unsigned)(vb[i] >> 32));
      }
#pragma unroll
      for (int cc = 0; cc < 4; ++cc) {
        float r = aR[cc], z = aZ[cc], n = aNh[cc];
#pragma unroll
        for (int j = 0; j < 8; ++j) {
          r = fdot2f(W[cc][1][j], g2[j], r);
          z = fdot2f(W[cc][3][j], g2[j], z);
          n = fdot2f(W[cc][5][j], g2[j], n);
        }
        aR[cc] = r; aZ[cc] = z; aNh[cc] = n;
      }
      float hn[4];
#pragma unroll
      for (int cc = 0; cc < 4; ++cc) {
        float4 s = reduce4(aR[cc], aZ[cc], aNx[cc], aNh[cc], lane);
        float r = sigm(s.x + bRv[cc]);
        float zz = sigm(s.y + bZv[cc]);
        float n = tanh_f(s.z + bNxv[cc] + r * (s.w + bNhv[cc]));
        hn[cc] = (1.f - zz) * n + zz * hprev[cc];
        hprev[cc] = hn[cc];
        ssum[cc] += hn[cc];
        ssq[cc] += hn[cc] * hn[cc];
      }
      if (lane == 0) {
        unsigned long long pk = pack4(hn[0], hn[1], hn[2], hn[3]);
        __hip_atomic_store(h2u + (size_t)t * 256 + (ch >> 2), pk,
                           __ATOMIC_RELAXED, __HIP_MEMORY_SCOPE_AGENT);
      }
    }
    if (lane == 0) {
#pragma unroll
      for (int cc = 0; cc < 4; ++cc) {
        sums[ch + cc] = ssum[cc];
        sums[HD + ch + cc] = ssq[cc];
      }
    }
  }
}

// y[t] = K + sum_c h2[t,c]*A[c];  A = rsqrt(var+eps)*gamma*fc_w,
// K = fc_b + sum_c (beta*fc_w - mu*A)
__launch_bounds__(256)
__global__ void fc_bn_kernel(const unsigned* __restrict__ h2u, const float* __restrict__ sums,
                             const float* __restrict__ gamma, const float* __restrict__ beta,
                             const float* __restrict__ fcw, const float* __restrict__ fcb,
                             float* __restrict__ out)
{
  const int tid = threadIdx.x;
  const int wave = tid >> 6;
  const int lane = tid & 63;
  float A[16];
  float kp = 0.f;
#pragma unroll
  for (int j = 0; j < 16; ++j) {
    const int c = 16 * lane + j;
    float mu = sums[c] * (1.f / TT);
    float var = fmaxf(sums[HD + c] * (1.f / TT) - mu * mu, 0.f);
    float rs = rsqrtf(var + 1e-5f);
    float a = rs * gamma[c] * fcw[c];
    A[j] = a;
    kp += beta[c] * fcw[c] - mu * a;
  }
#pragma unroll
  for (int m = 32; m >= 1; m >>= 1) kp += __shfl_xor(kp, m);
  const float K = kp + fcb[0];
  const int tbase = (blockIdx.x * 4 + wave) * 16;
  for (int mm = 0; mm < 16; ++mm) {
    const int t = tbase + mm;
    const unsigned* p = h2u + (size_t)(t + 1) * 512 + 8 * lane;
    float d = 0.f;
#pragma unroll
    for (int j = 0; j < 8; ++j) {
      h2_t hp = __builtin_bit_cast(h2_t, p[j]);
      d += (float)hp.x * A[2 * j] + (float)hp.y * A[2 * j + 1];
    }
#pragma unroll
    for (int m = 32; m >= 1; m >>= 1) d += __shfl_xor(d, m);
    if (lane == 0) out[t] = K + d;
  }
}

extern "C" void kernel_launch(void* const* d_in, const int* in_sizes, int n_in,
                              void* d_out, int out_size, void* d_ws, size_t ws_size,
                              hipStream_t stream) {
  const float* x    = (const float*)d_in[0];
  const float* wih0 = (const float*)d_in[1];
  const float* whh0 = (const float*)d_in[2];
  const float* bih0 = (const float*)d_in[3];
  const float* bhh0 = (const float*)d_in[4];
  const float* wih1 = (const float*)d_in[5];
  const float* whh1 = (const float*)d_in[6];
  const float* bih1 = (const float*)d_in[7];
  const float* bhh1 = (const float*)d_in[8];
  const float* gamma = (const float*)d_in[9];
  const float* beta  = (const float*)d_in[10];
  const float* fcw   = (const float*)d_in[11];
  const float* fcb   = (const float*)d_in[12];

  const size_t HIST = (size_t)(TT + 1) * HD * 2;   // 33,556,480 B per history
  unsigned long long* h1u = (unsigned long long*)d_ws;
  unsigned long long* h2u = (unsigned long long*)((char*)d_ws + HIST);
  float* sums = (float*)((char*)d_ws + 2 * HIST);

  // slot 0 = h[-1] = 0 ; slots 1..TT = f16 NaN sentinel (0x7F7F)
  hipMemsetAsync(h1u, 0, (size_t)HD * 2, stream);
  hipMemsetAsync((char*)h1u + HD * 2, 0x7F, (size_t)TT * HD * 2, stream);
  hipMemsetAsync(h2u, 0, (size_t)HD * 2, stream);
  hipMemsetAsync((char*)h2u + HD * 2, 0x7F, (size_t)TT * HD * 2, stream);

  gru_persistent<<<128, 256, 0, stream>>>(x, wih0, whh0, bih0, bhh0,
                                          wih1, whh1, bih1, bhh1,
                                          h1u, h2u, sums);
  fc_bn_kernel<<<256, 256, 0, stream>>>((const unsigned*)h2u, sums, gamma, beta, fcw, fcb,
                                        (float*)d_out);
}